// Round 7
// baseline (275.004 us; speedup 1.0000x reference)
//
#include <hip/hip_runtime.h>
#include <math.h>

// MelGaussianFilteredMSE:
//   diff = 10^(mo/10) - 10^(tg/10)            (B=32, F=1025, T=2000, fp32)
//   out  = mean( (M @ diff along F)^2 )       M is BANDED: half-width <= 10
//
// R6 "slab-stream": all prior kernels plateaued at ~1.6 TB/s with 0.5-1 KB
// contiguous chunks + 8 KB jumps scattered over 512 MB (DRAM page/channel
// thrash theory). This kernel makes each block's address stream CONTIGUOUS:
// a block owns (b, 64-row f-chunk) x the ENTIRE T axis -- 1024 threads,
// thread tau owns float2 column 2*tau. Each row-step reads one full 8000 B
// row of mo and tg; rows are adjacent in memory -> the block sweeps one
// contiguous ~1.4 MB slab per array (the 6.3 TB/s microbench pattern).
// FIR: per-thread 21-deep float2 window, PF=3 prefetch ring (static slots),
// coeffs in LDS via 6x ds_read_b128 per output row, zero-coeff edge trick.

#define B_N 32
#define F_N 1025
#define T_N 2000

#define FC   64            // output rows per chunk
#define ROWS 84            // FC + 20 halo = 4*21
#define NCH  17            // 17*64 = 1088 >= 1025
#define NT   1024          // threads per block; thread tau -> float2 col 2*tau
#define PF   3             // ring depth; 21 % 3 == 0 -> static slots
#define CST  24            // coeff LDS row stride (96 B)

#define K_E 0.33219280948873623f   // log2(10)/10 : 10^(x/10) = 2^(x*K_E)

__global__ __launch_bounds__(NT, 4)
void mel_mse_slab(const float* __restrict__ mo_g, const float* __restrict__ tg_g,
                  const float* __restrict__ M, float* __restrict__ partials) {
    __shared__ float sm[FC * CST];   // 6144 B
    __shared__ float red[NT];        // 4096 B

    const int tid  = threadIdx.x;
    const int f0   = blockIdx.x * FC;
    const int b    = blockIdx.y;
    const int base = f0 - 10;

    // ---- stage the 21-wide coefficient band, zero-padded (edges -> 0) ----
    for (int i = tid; i < FC * CST; i += NT) {
        const int row = i / CST;
        const int j   = i - row * CST;
        const int f   = f0 + row;
        const int k   = f - 10 + j;
        float v = 0.f;
        if (j < 21 && f < F_N && k >= 0 && k < F_N) v = M[(size_t)f * F_N + k];
        sm[i] = v;
    }
    __syncthreads();

    const bool act = (tid < T_N / 2);          // 1000 active float2 columns
    const int  tc  = act ? tid * 2 : 0;

    float2 w[21];                              // diff window (static-indexed)
    float2 ra[PF], rc[PF];                     // prefetch rings
    float2 acc = make_float2(0.f, 0.f);

    // issue stream row n into ring slot s (row math scalar/uniform)
    auto ISSUE = [&](int n, int s) {
        int nn = n > ROWS - 1 ? ROWS - 1 : n;              // tail over-issues
        int g  = base + nn;
        g = g < 0 ? 0 : (g > F_N - 1 ? F_N - 1 : g);       // OOB -> coeff is 0
        const size_t off = (size_t)(b * F_N + g) * T_N + tc;
        ra[s] = *reinterpret_cast<const float2*>(mo_g + off);
        rc[s] = *reinterpret_cast<const float2*>(tg_g + off);
    };
    auto CONS = [&](int s, int ws) {
        const float2 a = ra[s], c = rc[s];
        w[ws].x = exp2f(a.x * K_E) - exp2f(c.x * K_E);
        w[ws].y = exp2f(a.y * K_E) - exp2f(c.y * K_E);
    };
    // emit chunk-local output row r_out; s0 = window slot of tap 0 (static)
    auto OUT = [&](int r_out, int s0) {
        float cf[24];
        const float4* c4 = reinterpret_cast<const float4*>(&sm[r_out * CST]);
#pragma unroll
        for (int q = 0; q < 6; ++q)
            *reinterpret_cast<float4*>(&cf[4 * q]) = c4[q];  // ds_read_b128 x6
        float2 o = make_float2(0.f, 0.f);
#pragma unroll
        for (int j = 0; j < 21; ++j) {
            const float2 wv = w[(s0 + j) % 21];
            o.x = fmaf(cf[j], wv.x, o.x);
            o.y = fmaf(cf[j], wv.y, o.y);
        }
        acc.x = fmaf(o.x, o.x, acc.x);
        acc.y = fmaf(o.y, o.y, acc.y);
    };

    // ---- prologue: rows 0..2 in flight ----
#pragma unroll
    for (int i = 0; i < PF; ++i) ISSUE(i, i);

    // ---- macro-block 0 (rows 0..20): fill window, first output at i==20 ----
#pragma unroll
    for (int i = 0; i < 21; ++i) {
        CONS(i % PF, i);
        ISSUE(i + PF, i % PF);                 // rows 3..23
        if (i == 20) OUT(0, 0);
    }
    // ---- macro-blocks 1..3 (rows 21..83), one output per row ----
    for (int mb = 1; mb < 4; ++mb) {
        const int nb = mb * 21;                // 21 % PF == 0 -> slot = i % PF
#pragma unroll
        for (int i = 0; i < 21; ++i) {
            CONS(i % PF, i);
            ISSUE(nb + i + PF, i % PF);
            OUT(nb + i - 20, (i + 1) % 21);
        }
    }

    // ---- block reduction ----
    red[tid] = act ? (acc.x + acc.y) : 0.f;
    __syncthreads();
    for (int s = NT / 2; s > 0; s >>= 1) {
        if (tid < s) red[tid] += red[tid + s];
        __syncthreads();
    }
    if (tid == 0) {
        const int bid = blockIdx.x + gridDim.x * blockIdx.y;
        partials[bid] = red[0];
    }
}

__global__ void mel_mse_reduce(const float* __restrict__ partials, int n,
                               float* __restrict__ out) {
    __shared__ double red[256];
    double s = 0.0;
    for (int i = threadIdx.x; i < n; i += 256) s += (double)partials[i];
    red[threadIdx.x] = s;
    __syncthreads();
    for (int st = 128; st > 0; st >>= 1) {
        if (threadIdx.x < st) red[threadIdx.x] += red[threadIdx.x + st];
        __syncthreads();
    }
    if (threadIdx.x == 0)
        out[0] = (float)(red[0] / (double)((long long)B_N * F_N * T_N));
}

extern "C" void kernel_launch(void* const* d_in, const int* in_sizes, int n_in,
                              void* d_out, int out_size, void* d_ws, size_t ws_size,
                              hipStream_t stream) {
    const float* mo = (const float*)d_in[0];   // model_output (32,1025,2000) fp32
    const float* tg = (const float*)d_in[1];   // target       (32,1025,2000) fp32
    const float* M  = (const float*)d_in[2];   // transform_matrix (1025,1025) fp32
    float* out      = (float*)d_out;
    float* partials = (float*)d_ws;            // 544*4 = 2176 B

    dim3 grid(NCH, B_N);                       // 17 f-chunks x 32 batches = 544
    const int nparts = NCH * B_N;

    mel_mse_slab<<<grid, NT, 0, stream>>>(mo, tg, M, partials);
    mel_mse_reduce<<<1, 256, 0, stream>>>(partials, nparts, out);
}

// Round 8
// 132.017 us; speedup vs baseline: 2.0831x; 2.0831x over previous
//
#include <hip/hip_runtime.h>
#include <math.h>

// MelGaussianFilteredMSE:
//   diff = 10^(mo/10) - 10^(tg/10)            (B=32, F=1025, T=2000, fp32)
//   out  = mean( (M @ diff along F)^2 )       M is BANDED: half-width <= 10
//
// R7: EXACT R1 structure (the 131 us best: NOUT=106, CT=512, NT=256,
// launch_bounds(256,4), masked single-path loads, load->use streaming, no
// ring) with ONE change: per-output-row coefficient reads are 6x
// ds_read_b128 into statically-indexed registers instead of 21x ds_read_b32
// (R1's LDS issue pressure was its top non-memory cost). R2 tested this
// confounded with a NOUT change that doubled FETCH; this isolates it.

#define B_N 32
#define F_N 1025
#define T_N 2000

#define NOUT   106   // output rows per f-chunk; streamed rows = 126 = 6*21
#define NCHUNK 10
#define NT     256   // threads per block
#define CT     512   // t-columns per block (256 threads * 2)
#define CST    24    // coeff LDS row stride (96 B, float4-aligned)

#define LOG2_10_DIV10 0.33219280948873623f   // 10^(x/10) = 2^(x*this)

__global__ __launch_bounds__(NT, 4)
void mel_mse_stream(const float* __restrict__ mo_g, const float* __restrict__ tg_g,
                    const float* __restrict__ M, float* __restrict__ partials) {
    __shared__ float sm[NOUT * CST];   // 106*24*4 = 10176 B
    __shared__ float red[NT];          //             1024 B

    const int tid = threadIdx.x;
    const int t0  = blockIdx.x * CT;
    const int f0  = blockIdx.y * NOUT;
    const int b   = blockIdx.z;
    const int t   = t0 + tid * 2;
    const bool active = (t + 1 < T_N);       // T_N even: both cols valid or neither

    // ---- stage the 21-wide coefficient band (pad lanes j=21..23 zeroed) ----
    for (int i = tid; i < NOUT * CST; i += NT) {
        const int row = i / CST;
        const int j   = i - row * CST;
        const int f   = f0 + row;
        const int k   = f - 10 + j;
        float v = 0.0f;
        if (j < 21 && f < F_N && k >= 0 && k < F_N) v = M[(size_t)f * F_N + k];
        sm[i] = v;
    }
    __syncthreads();

    const int    tc      = active ? t : 0;
    const size_t colbase = ((size_t)b * F_N) * (size_t)T_N + tc;
    const int    base    = f0 - 10;          // global row of stream step 0

    float2 w[21];                            // rolling window, static-indexed only
    float  acc = 0.f;

    auto LOAD = [&](int r) -> float2 {
        int g = base + r;
        const float mask = (active && g >= 0 && g < F_N) ? 1.f : 0.f;
        g = g < 0 ? 0 : (g >= F_N ? F_N - 1 : g);
        const size_t off = colbase + (size_t)g * T_N;
        const float2 a = *reinterpret_cast<const float2*>(mo_g + off);
        const float2 c = *reinterpret_cast<const float2*>(tg_g + off);
        float2 d;
        d.x = (exp2f(a.x * LOG2_10_DIV10) - exp2f(c.x * LOG2_10_DIV10)) * mask;
        d.y = (exp2f(a.y * LOG2_10_DIV10) - exp2f(c.y * LOG2_10_DIV10)) * mask;
        return d;
    };
    // output row r_out (local); s0 = window slot holding tap 0 (compile-time)
    auto OUT = [&](int r_out, int s0) {
        if (f0 + r_out < F_N) {              // uniform runtime branch
            float cf[24];                    // statically indexed -> registers
            const float4* c4 = reinterpret_cast<const float4*>(&sm[r_out * CST]);
#pragma unroll
            for (int q = 0; q < 6; ++q)
                *reinterpret_cast<float4*>(&cf[4 * q]) = c4[q];  // ds_read_b128 x6
            float2 o = make_float2(0.f, 0.f);
#pragma unroll
            for (int j = 0; j < 21; ++j) {
                const float2 wv = w[(s0 + j) % 21];
                o.x = fmaf(cf[j], wv.x, o.x);
                o.y = fmaf(cf[j], wv.y, o.y);
            }
            acc = fmaf(o.x, o.x, fmaf(o.y, o.y, acc));
        }
    };

    // ---- prologue: stream rows 0..20, emit output row 0 ----
#pragma unroll
    for (int i = 0; i < 21; ++i) w[i] = LOAD(i);
    OUT(0, 0);

    // ---- steady state: 5 macro-iterations of 21 rows ----
    for (int m = 1; m < 6; ++m) {
        const int rb = m * 21;
#pragma unroll
        for (int i = 0; i < 21; ++i) {
            w[i] = LOAD(rb + i);             // slot (rb+i)%21 == i
            OUT(rb + i - 20, (i + 1) % 21);  // static slot base
        }
    }

    // ---- block reduction ----
    red[tid] = acc;
    __syncthreads();
    for (int s = NT / 2; s > 0; s >>= 1) {
        if (tid < s) red[tid] += red[tid + s];
        __syncthreads();
    }
    if (tid == 0) {
        const int bid = blockIdx.x + gridDim.x * (blockIdx.y + gridDim.y * blockIdx.z);
        partials[bid] = red[0];
    }
}

__global__ void mel_mse_reduce(const float* __restrict__ partials, int n,
                               float* __restrict__ out) {
    __shared__ double red[256];
    double s = 0.0;
    for (int i = threadIdx.x; i < n; i += 256) s += (double)partials[i];
    red[threadIdx.x] = s;
    __syncthreads();
    for (int st = 128; st > 0; st >>= 1) {
        if (threadIdx.x < st) red[threadIdx.x] += red[threadIdx.x + st];
        __syncthreads();
    }
    if (threadIdx.x == 0)
        out[0] = (float)(red[0] / (double)((long long)B_N * F_N * T_N));
}

extern "C" void kernel_launch(void* const* d_in, const int* in_sizes, int n_in,
                              void* d_out, int out_size, void* d_ws, size_t ws_size,
                              hipStream_t stream) {
    const float* mo = (const float*)d_in[0];   // model_output (32,1025,2000) fp32
    const float* tg = (const float*)d_in[1];   // target       (32,1025,2000) fp32
    const float* M  = (const float*)d_in[2];   // transform_matrix (1025,1025) fp32
    float* out      = (float*)d_out;           // scalar fp32
    float* partials = (float*)d_ws;            // 4*10*32*4 = 5120 B of d_ws

    dim3 grid((T_N + CT - 1) / CT,             // 4 t-tiles
              NCHUNK,                          // 10 f-chunks
              B_N);                            // 32 batches
    const int nparts = grid.x * grid.y * grid.z;

    mel_mse_stream<<<grid, NT, 0, stream>>>(mo, tg, M, partials);
    mel_mse_reduce<<<1, 256, 0, stream>>>(partials, nparts, out);
}

// Round 9
// 124.631 us; speedup vs baseline: 2.2066x; 1.0593x over previous
//
#include <hip/hip_runtime.h>
#include <math.h>

// MelGaussianFilteredMSE:
//   diff = 10^(mo/10) - 10^(tg/10)            (B=32, F=1025, T=2000, fp32)
//   out  = mean( (M @ diff along F)^2 )       M is BANDED: half-width <= 10
//
// R8 = R7 skeleton (NOUT=106, CT=512, NT=256, lb(256,4), same grid/order --
// the config with best L3 retention, FETCH=314MB) + two latency fixes:
//  - PF=3 prefetch ring on stream loads (3 load-pairs in flight per wave,
//    was 1: OUT consumed the same-step load)
//  - coeffs from a pre-packed band via wave-uniform loads -> s_load/SGPRs
//    (lgkmcnt, zero vmcnt traffic, zero LDS in main loop, frees cf VGPRs)
// OUT branch-free: rows f>=1025 and OOB halo rows have all-zero coeffs.

#define B_N 32
#define F_N 1025
#define T_N 2000

#define NOUT   106   // output rows per f-chunk; streamed rows = 126 = 6*21
#define ROWS   126
#define NCHUNK 10
#define NT     256   // threads per block
#define CT     512   // t-columns per block (256 threads * 2)
#define PF     3     // ring depth; 21 % 3 == 0 -> static slots
#define CBS    24    // band row stride in floats (96 B, float4-aligned)
#define BANDROWS (NCHUNK * NOUT)     // 1060 rows; rows >= 1025 all-zero

#define K_E 0.33219280948873623f     // log2(10)/10 : 10^(x/10) = 2^(x*K_E)

__global__ void build_band(const float* __restrict__ M, float* __restrict__ band) {
    const int idx = blockIdx.x * 256 + threadIdx.x;
    if (idx >= BANDROWS * CBS) return;
    const int f = idx / CBS;
    const int j = idx - f * CBS;
    const int k = f - 10 + j;
    float v = 0.f;
    if (j < 21 && f < F_N && k >= 0 && k < F_N) v = M[(size_t)f * F_N + k];
    band[idx] = v;
}

__global__ __launch_bounds__(NT, 4)
void mel_mse_stream(const float* __restrict__ mo_g, const float* __restrict__ tg_g,
                    const float* __restrict__ band, float* __restrict__ partials) {
    __shared__ float red[NT];

    const int tid = threadIdx.x;
    const int t0  = blockIdx.x * CT;
    const int f0  = blockIdx.y * NOUT;   // uniform
    const int b   = blockIdx.z;          // uniform
    const int t   = t0 + tid * 2;
    const bool colv = (t + 1 < T_N);     // T_N even: pair fully valid or not
    const int  tc   = colv ? t : 0;
    const int  base = f0 - 10;

    const size_t colbase = ((size_t)b * F_N) * (size_t)T_N + tc;

    float2 w[21];                        // diff window (static-indexed)
    float2 ra[PF], rc[PF];               // raw prefetch rings
    float  acc = 0.f;

    // issue stream row n into ring slot s; row math is scalar/uniform
    auto ISSUE = [&](int n, int s) {
        int g = base + n;
        g = g < 0 ? 0 : (g > F_N - 1 ? F_N - 1 : g);   // OOB -> coeff is 0
        const size_t off = colbase + (size_t)g * T_N;
        ra[s] = *reinterpret_cast<const float2*>(mo_g + off);
        rc[s] = *reinterpret_cast<const float2*>(tg_g + off);
    };
    auto CONS = [&](int s, int ws) {
        const float2 a = ra[s], c = rc[s];
        w[ws].x = exp2f(a.x * K_E) - exp2f(c.x * K_E);
        w[ws].y = exp2f(a.y * K_E) - exp2f(c.y * K_E);
    };
    // emit global output row frow; s0 = window slot of tap 0 (compile-time).
    // Coeff address is uniform -> s_load into SGPRs; FMA reads s-operand.
    auto OUT = [&](int frow, int s0) {
        const float4* c4 = reinterpret_cast<const float4*>(band + (size_t)frow * CBS);
        float cf[24];
#pragma unroll
        for (int q = 0; q < 6; ++q)
            *reinterpret_cast<float4*>(&cf[4 * q]) = c4[q];
        float2 o = make_float2(0.f, 0.f);
#pragma unroll
        for (int j = 0; j < 21; ++j) {
            const float2 wv = w[(s0 + j) % 21];
            o.x = fmaf(cf[j], wv.x, o.x);
            o.y = fmaf(cf[j], wv.y, o.y);
        }
        acc = fmaf(o.x, o.x, fmaf(o.y, o.y, acc));
    };

    // ---- prologue: rows 0..2 in flight ----
#pragma unroll
    for (int i = 0; i < PF; ++i) ISSUE(i, i);

    // ---- macro 0 (rows 0..20): fill window; first output at i==20 ----
#pragma unroll
    for (int i = 0; i < 21; ++i) {
        CONS(i % PF, i);
        ISSUE(i + PF, i % PF);                    // rows 3..23
        if (i == 20) OUT(f0, 0);
    }
    // ---- macros 1..5 (rows 21..125): one output per row ----
    // (last macro's final 3 issues are dead -> DCE'd; addresses clamped)
    for (int m = 1; m < 6; ++m) {
        const int nb = m * 21;
#pragma unroll
        for (int i = 0; i < 21; ++i) {
            CONS(i % PF, i);
            ISSUE(nb + i + PF, i % PF);
            OUT(f0 + nb + i - 20, (i + 1) % 21);  // static slot base
        }
    }

    // ---- block reduction ----
    red[tid] = colv ? acc : 0.f;
    __syncthreads();
    for (int s = NT / 2; s > 0; s >>= 1) {
        if (tid < s) red[tid] += red[tid + s];
        __syncthreads();
    }
    if (tid == 0) {
        const int bid = blockIdx.x + gridDim.x * (blockIdx.y + gridDim.y * blockIdx.z);
        partials[bid] = red[0];
    }
}

__global__ void mel_mse_reduce(const float* __restrict__ partials, int n,
                               float* __restrict__ out) {
    __shared__ double red[256];
    double s = 0.0;
    for (int i = threadIdx.x; i < n; i += 256) s += (double)partials[i];
    red[threadIdx.x] = s;
    __syncthreads();
    for (int st = 128; st > 0; st >>= 1) {
        if (threadIdx.x < st) red[threadIdx.x] += red[threadIdx.x + st];
        __syncthreads();
    }
    if (threadIdx.x == 0)
        out[0] = (float)(red[0] / (double)((long long)B_N * F_N * T_N));
}

extern "C" void kernel_launch(void* const* d_in, const int* in_sizes, int n_in,
                              void* d_out, int out_size, void* d_ws, size_t ws_size,
                              hipStream_t stream) {
    const float* mo = (const float*)d_in[0];   // model_output (32,1025,2000) fp32
    const float* tg = (const float*)d_in[1];   // target       (32,1025,2000) fp32
    const float* M  = (const float*)d_in[2];   // transform_matrix (1025,1025) fp32
    float* out      = (float*)d_out;

    float* band     = (float*)d_ws;                      // 1060*24*4 = 101760 B
    float* partials = (float*)((char*)d_ws + 102400);    // 1280*4    =   5120 B

    build_band<<<(BANDROWS * CBS + 255) / 256, 256, 0, stream>>>(M, band);

    dim3 grid((T_N + CT - 1) / CT,             // 4 t-tiles
              NCHUNK,                          // 10 f-chunks
              B_N);                            // 32 batches -> 1280 blocks
    const int nparts = grid.x * grid.y * grid.z;

    mel_mse_stream<<<grid, NT, 0, stream>>>(mo, tg, band, partials);
    mel_mse_reduce<<<1, 256, 0, stream>>>(partials, nparts, out);
}